// Round 4
// baseline (268.374 us; speedup 1.0000x reference)
//
#include <hip/hip_runtime.h>
#include <stdint.h>

typedef __bf16 bf16;
typedef __bf16 bf16x2 __attribute__((ext_vector_type(2)));
typedef __bf16 bf16x4 __attribute__((ext_vector_type(4)));
typedef __bf16 bf16x8 __attribute__((ext_vector_type(8)));
typedef float f32x4 __attribute__((ext_vector_type(4)));

#define D_MODEL 1024
#define NHEADS 16
#define HEADDIM 64
#define SEQ 2048
#define NBATCH 2

__device__ __forceinline__ void async_load16(const void* g, void* l) {
  __builtin_amdgcn_global_load_lds(
      (__attribute__((address_space(1))) void*)g,
      (__attribute__((address_space(3))) void*)l, 16, 0, 0);
}

__device__ __forceinline__ float fexp2(float x) {
#if __has_builtin(__builtin_amdgcn_exp2f)
  return __builtin_amdgcn_exp2f(x);
#else
  return exp2f(x);
#endif
}

// ---------------- LayerNorm: fp32 x -> bf16 y ----------------
__global__ __launch_bounds__(256)
void ln_kernel(const float* __restrict__ x, const float* __restrict__ w,
               const float* __restrict__ b, bf16* __restrict__ y) {
  int row = blockIdx.x;
  int t = threadIdx.x;
  const float4 v = ((const float4*)(x + (size_t)row * D_MODEL))[t];
  float s = v.x + v.y + v.z + v.w;
  float sq = v.x * v.x + v.y * v.y + v.z * v.z + v.w * v.w;
#pragma unroll
  for (int d = 1; d < 64; d <<= 1) {
    s += __shfl_xor(s, d);
    sq += __shfl_xor(sq, d);
  }
  __shared__ float ps[4], pq[4];
  if ((t & 63) == 0) { ps[t >> 6] = s; pq[t >> 6] = sq; }
  __syncthreads();
  s = ps[0] + ps[1] + ps[2] + ps[3];
  sq = pq[0] + pq[1] + pq[2] + pq[3];
  float mean = s * (1.0f / D_MODEL);
  float var = sq * (1.0f / D_MODEL) - mean * mean;
  float rstd = rsqrtf(var + 1e-5f);
  float4 wv = ((const float4*)w)[t];
  float4 bv = ((const float4*)b)[t];
  bf16x4 o;
  o[0] = (bf16)((v.x - mean) * rstd * wv.x + bv.x);
  o[1] = (bf16)((v.y - mean) * rstd * wv.y + bv.y);
  o[2] = (bf16)((v.z - mean) * rstd * wv.z + bv.z);
  o[3] = (bf16)((v.w - mean) * rstd * wv.w + bv.w);
  ((bf16x4*)(y + (size_t)row * D_MODEL))[t] = o;
}

// ------------- transpose + cast: src fp32 [R][C] -> dst bf16 [C][R] -------------
__global__ __launch_bounds__(256)
void transpose_cast(const float* __restrict__ src, bf16* __restrict__ dst,
                    int src_ld, int dst_ld, int tiles_c,
                    long src_bstride, long dst_bstride) {
  __shared__ float tile[64][65];
  int tr = blockIdx.x / tiles_c, tc = blockIdx.x % tiles_c;
  const float* s = src + (long)blockIdx.y * src_bstride + (size_t)(tr * 64) * src_ld + (size_t)tc * 64;
  bf16* d = dst + (long)blockIdx.y * dst_bstride + (size_t)(tc * 64) * dst_ld + (size_t)tr * 64;
  int t = threadIdx.x;
  int rr = t >> 4;
  int cc = (t & 15) << 2;
#pragma unroll
  for (int i = 0; i < 4; ++i) {
    float4 v = *(const float4*)&s[(size_t)(rr + i * 16) * src_ld + cc];
    tile[rr + i * 16][cc + 0] = v.x;
    tile[rr + i * 16][cc + 1] = v.y;
    tile[rr + i * 16][cc + 2] = v.z;
    tile[rr + i * 16][cc + 3] = v.w;
  }
  __syncthreads();
#pragma unroll
  for (int i = 0; i < 4; ++i) {
    int drow = rr + i * 16;
    bf16x4 o;
    o[0] = (bf16)tile[cc + 0][drow];
    o[1] = (bf16)tile[cc + 1][drow];
    o[2] = (bf16)tile[cc + 2][drow];
    o[3] = (bf16)tile[cc + 3][drow];
    *(bf16x4*)&d[(size_t)drow * dst_ld + cc] = o;
  }
}

// ------------- GEMM: C[M][N] = A[M][K=1024] * Bt[N][K=1024]^T -------------
template <int MODE>
__global__ __launch_bounds__(256)
void gemm_bt(const bf16* __restrict__ A, const bf16* __restrict__ Bt,
             int ntn, void* __restrict__ p0, const void* __restrict__ p1) {
  __shared__ __align__(16) bf16 As[128 * 64];
  __shared__ __align__(16) bf16 Bs[128 * 64];
  int bm = blockIdx.x / ntn;
  int bn = blockIdx.x % ntn;
  int t = threadIdx.x;
  int w = t >> 6, l = t & 63;
  int lg = l >> 4, lo = l & 15;
  int wr = w >> 1, wc = w & 1;
  const bf16* Ab = A + (size_t)bm * 128 * 1024;
  const bf16* Bb = Bt + (size_t)bn * 128 * 1024;
  f32x4 acc[4][4];
#pragma unroll
  for (int i = 0; i < 4; ++i)
#pragma unroll
    for (int j = 0; j < 4; ++j) acc[i][j] = (f32x4){0.f, 0.f, 0.f, 0.f};

  for (int k0 = 0; k0 < 1024; k0 += 64) {
#pragma unroll
    for (int i = 0; i < 4; ++i) {
      int flat = i * 2048 + t * 8;
      int row = flat >> 6, col = flat & 63;
      async_load16(Ab + (size_t)row * 1024 + k0 + col, &As[i * 2048 + w * 512]);
      async_load16(Bb + (size_t)row * 1024 + k0 + col, &Bs[i * 2048 + w * 512]);
    }
    __syncthreads();
#pragma unroll
    for (int kk = 0; kk < 2; ++kk) {
      bf16x8 af[4], bfr[4];
#pragma unroll
      for (int i = 0; i < 4; ++i)
        af[i] = *(const bf16x8*)&As[(wr * 64 + i * 16 + lo) * 64 + kk * 32 + 8 * lg];
#pragma unroll
      for (int j = 0; j < 4; ++j)
        bfr[j] = *(const bf16x8*)&Bs[(wc * 64 + j * 16 + lo) * 64 + kk * 32 + 8 * lg];
#pragma unroll
      for (int i = 0; i < 4; ++i)
#pragma unroll
        for (int j = 0; j < 4; ++j)
          acc[i][j] = __builtin_amdgcn_mfma_f32_16x16x32_bf16(af[i], bfr[j], acc[i][j], 0, 0, 0);
    }
    __syncthreads();
  }

  int mbase = bm * 128 + wr * 64;
  int nbase = bn * 128 + wc * 64;
#pragma unroll
  for (int i = 0; i < 4; ++i) {
#pragma unroll
    for (int j = 0; j < 4; ++j) {
#pragma unroll
      for (int r = 0; r < 4; ++r) {
        int row = mbase + i * 16 + lg * 4 + r;
        int col = nbase + j * 16 + lo;
        float v = acc[i][j][r];
        if (MODE == 0) {
          bf16* dst = (bf16*)p0;
          int c = col;
          if (c >= 1024) { dst = (bf16*)((void*)p1); c -= 1024; }
          int h = c >> 6, e = c & 63;
          dst[((((size_t)(row >> 11) * NHEADS + h) * SEQ) + (row & 2047)) * HEADDIM + e] = (bf16)v;
        } else if (MODE == 1) {
          int h = row >> 6, e = row & 63;
          int b_ = col >> 11, s_ = col & 2047;
          ((bf16*)p0)[(((size_t)b_ * NHEADS + h) * HEADDIM + e) * SEQ + s_] = (bf16)v;
        } else {
          float xr = ((const float*)p1)[(size_t)row * 1024 + col];
          ((float*)p0)[(size_t)row * 1024 + col] = v + xr;
        }
      }
    }
  }
}

// ------------- causal flash attention v4 -------------
// No K/V LDS staging (K/V L2-fits: 512 KB per bh, 16 MB total) -> no barriers,
// waves run free. V fragment loads issued before softmax (latency hides under
// VALU chain). XCD-grouped block mapping: all 32 q-tiles of a bh on one XCD
// (L2 working set 2 MB < 4 MB). Swapped QK^T + in-lane softmax + defer-max
// and the per-wave LDS P round-trip kept from v3.
__global__ __launch_bounds__(256)
void attn_kernel(const bf16* __restrict__ q, const bf16* __restrict__ k,
                 const bf16* __restrict__ vt, bf16* __restrict__ attn) {
  __shared__ __align__(16) bf16 P[4][16 * 64];
  const float C2 = 0.125f * 1.44269504f;  // fold 1/sqrt(64) into exp2 arg
  // block decode: i = xcd-grouped; bh = (i&7) + 8*(slot>>5) pins a bh's 32
  // tiles to one XCD (assumes round-robin dispatch i -> XCD i%8).
  int i = blockIdx.x;
  int slot = i >> 3;
  int bh = (i & 7) + 8 * (slot >> 5);
  int tile = 31 - (slot & 31);  // heavy causal tiles first within group
  int b = bh >> 4, h = bh & 15;
  int t = threadIdx.x, w = t >> 6, l = t & 63;
  int lg = l >> 4, lo = l & 15;
  const bf16* qp = q + (size_t)bh * SEQ * HEADDIM;
  const bf16* kp = k + (size_t)bh * SEQ * HEADDIM;
  const bf16* vp = vt + (size_t)bh * HEADDIM * SEQ;
  int q0 = tile * 64 + w * 16;

  bf16x8 qf0 = *(const bf16x8*)&qp[(size_t)(q0 + lo) * HEADDIM + 8 * lg];
  bf16x8 qf1 = *(const bf16x8*)&qp[(size_t)(q0 + lo) * HEADDIM + 32 + 8 * lg];

  f32x4 o[4];
#pragma unroll
  for (int nt = 0; nt < 4; ++nt) o[nt] = (f32x4){0.f, 0.f, 0.f, 0.f};
  float m = -1e30f, lsum = 0.f;  // per-lane, q-row = q0 + lo (raw-score units)
  int diag_rhs = w * 16 + lo;    // kv-local visibility bound on diagonal chunk

  for (int c = 0; c <= tile; ++c) {
    int kv0 = c * 64;

    // S^T = K * Q^T : C[kv][q], lane owns q = lo, kv = 16*nt + 4*lg + r
    f32x4 s[4];
    __builtin_amdgcn_s_setprio(1);
#pragma unroll
    for (int nt = 0; nt < 4; ++nt) {
      s[nt] = (f32x4){0.f, 0.f, 0.f, 0.f};
      const bf16* kr = &kp[(size_t)(kv0 + nt * 16 + lo) * HEADDIM];
      bf16x8 kf0 = *(const bf16x8*)&kr[8 * lg];
      bf16x8 kf1 = *(const bf16x8*)&kr[32 + 8 * lg];
      s[nt] = __builtin_amdgcn_mfma_f32_16x16x32_bf16(kf0, qf0, s[nt], 0, 0, 0);
      s[nt] = __builtin_amdgcn_mfma_f32_16x16x32_bf16(kf1, qf1, s[nt], 0, 0, 0);
    }
    __builtin_amdgcn_s_setprio(0);

    // issue V fragment loads now; latency hides under the softmax VALU chain
    bf16x8 vf0[4], vf1[4];
#pragma unroll
    for (int nt = 0; nt < 4; ++nt) {
      const bf16* vr = &vp[(size_t)(nt * 16 + lo) * SEQ + kv0];
      vf0[nt] = *(const bf16x8*)&vr[8 * lg];
      vf1[nt] = *(const bf16x8*)&vr[32 + 8 * lg];
    }

    if (c == tile) {  // causal mask, diagonal chunk only (uniform branch)
#pragma unroll
      for (int nt = 0; nt < 4; ++nt)
#pragma unroll
        for (int r = 0; r < 4; ++r)
          s[nt][r] = (16 * nt + 4 * lg + r <= diag_rhs) ? s[nt][r] : -1e30f;
    }

    // in-lane max tree (16 values) + 2 cross-group shuffles
    float mx0 = fmaxf(fmaxf(s[0][0], s[0][1]), fmaxf(s[0][2], s[0][3]));
    float mx1 = fmaxf(fmaxf(s[1][0], s[1][1]), fmaxf(s[1][2], s[1][3]));
    float mx2 = fmaxf(fmaxf(s[2][0], s[2][1]), fmaxf(s[2][2], s[2][3]));
    float mx3 = fmaxf(fmaxf(s[3][0], s[3][1]), fmaxf(s[3][2], s[3][3]));
    float pmax = fmaxf(fmaxf(mx0, mx1), fmaxf(mx2, mx3));
    pmax = fmaxf(pmax, __shfl_xor(pmax, 16));
    pmax = fmaxf(pmax, __shfl_xor(pmax, 32));

    // defer-max: rescale only if some row's max grew past threshold (40 raw = 5 nats)
    if (__any(pmax > m + 40.0f)) {
      float mn = fmaxf(m, pmax);
      float alpha = fexp2((m - mn) * C2);
      m = mn;
      lsum *= alpha;
#pragma unroll
      for (int r = 0; r < 4; ++r) {
        float ar = __shfl(alpha, (l & 48) | (4 * lg + r));
        o[0][r] *= ar; o[1][r] *= ar; o[2][r] *= ar; o[3][r] *= ar;
      }
    }

    float mC = m * C2;
    float p[4][4];
    float psum[4];
#pragma unroll
    for (int nt = 0; nt < 4; ++nt) {
      psum[nt] = 0.f;
#pragma unroll
      for (int r = 0; r < 4; ++r) {
        float e = fexp2(fmaf(s[nt][r], C2, -mC));
        p[nt][r] = e;
        psum[nt] += e;
      }
    }
    float pst = (psum[0] + psum[1]) + (psum[2] + psum[3]);
    pst += __shfl_xor(pst, 16);
    pst += __shfl_xor(pst, 32);
    lsum += pst;

    // P[q=lo][kv] -> per-wave LDS (swizzled), packed b32 writes
#pragma unroll
    for (int nt = 0; nt < 4; ++nt) {
      int chunk = (2 * nt + (lg >> 1)) ^ (lo & 7);
      int base = lo * 64 + chunk * 8 + 4 * (lg & 1);
      bf16x2 w0, w1;
      w0[0] = (bf16)p[nt][0]; w0[1] = (bf16)p[nt][1];
      w1[0] = (bf16)p[nt][2]; w1[1] = (bf16)p[nt][3];
      *(bf16x2*)&P[w][base] = w0;
      *(bf16x2*)&P[w][base + 2] = w1;
    }
    bf16x8 pf0 = *(const bf16x8*)&P[w][lo * 64 + ((lg ^ (lo & 7)) * 8)];
    bf16x8 pf1 = *(const bf16x8*)&P[w][lo * 64 + (((4 + lg) ^ (lo & 7)) * 8)];

    __builtin_amdgcn_s_setprio(1);
#pragma unroll
    for (int nt = 0; nt < 4; ++nt) {
      o[nt] = __builtin_amdgcn_mfma_f32_16x16x32_bf16(pf0, vf0[nt], o[nt], 0, 0, 0);
      o[nt] = __builtin_amdgcn_mfma_f32_16x16x32_bf16(pf1, vf1[nt], o[nt], 0, 0, 0);
    }
    __builtin_amdgcn_s_setprio(0);
  }

#pragma unroll
  for (int r = 0; r < 4; ++r) {
    float ls = __shfl(lsum, (l & 48) | (4 * lg + r));
    float inv = 1.0f / ls;
    int qrow = q0 + 4 * lg + r;
#pragma unroll
    for (int nt = 0; nt < 4; ++nt)
      attn[((size_t)b * SEQ + qrow) * D_MODEL + h * HEADDIM + nt * 16 + lo] =
          (bf16)(o[nt][r] * inv);
  }
}

extern "C" void kernel_launch(void* const* d_in, const int* in_sizes, int n_in,
                              void* d_out, int out_size, void* d_ws, size_t ws_size,
                              hipStream_t stream) {
  const float* x = (const float*)d_in[0];
  const float* ln_w = (const float*)d_in[1];
  const float* ln_b = (const float*)d_in[2];
  const float* wq = (const float*)d_in[3];
  const float* wk = (const float*)d_in[4];
  const float* wv = (const float*)d_in[5];
  const float* wo = (const float*)d_in[6];
  float* out = (float*)d_out;
  char* ws = (char*)d_ws;

  bf16* y     = (bf16*)(ws);                     // 8 MB
  bf16* WqkvT = (bf16*)(ws + (8u << 20));        // 6 MB  [3072][1024]
  bf16* woT   = (bf16*)(ws + (14u << 20));       // 2 MB  [1024][1024]
  bf16* qb    = (bf16*)(ws + (16u << 20));       // 8 MB  [b][h][s][e]
  bf16* kb    = (bf16*)(ws + (24u << 20));       // 8 MB  [b][h][s][e]
  bf16* vtb   = (bf16*)(ws + (32u << 20));       // 8 MB  [b][h][e][s]
  bf16* attn  = (bf16*)(ws + (40u << 20));       // 8 MB  [b*s][h*e]

  // LayerNorm
  ln_kernel<<<NBATCH * SEQ, 256, 0, stream>>>(x, ln_w, ln_b, y);

  // weights -> k-contiguous bf16 transposes
  transpose_cast<<<dim3(16, 16), 256, 0, stream>>>(wq, WqkvT,                64, 1024, 1, 65536, 65536);
  transpose_cast<<<dim3(16, 16), 256, 0, stream>>>(wk, WqkvT + (1u << 20),   64, 1024, 1, 65536, 65536);
  transpose_cast<<<dim3(16, 16), 256, 0, stream>>>(wv, WqkvT + (2u << 20),   64, 1024, 1, 65536, 65536);
  transpose_cast<<<dim3(256, 1), 256, 0, stream>>>(wo, woT,                1024, 1024, 16, 0, 0);

  // q,k projections: [4096,1024] x [2048,1024]^T
  gemm_bt<0><<<32 * 16, 256, 0, stream>>>(y, WqkvT, 16, qb, kb);
  // v^T projection: [1024,1024] x [4096,1024]^T -> vt[b][h][e][s]
  gemm_bt<1><<<8 * 32, 256, 0, stream>>>(WqkvT + (2u << 20), y, 32, vtb, nullptr);

  // causal flash attention (1024 blocks, XCD-grouped decode in-kernel)
  attn_kernel<<<dim3(1024), 256, 0, stream>>>(qb, kb, vtb, attn);

  // output projection + residual: [4096,1024] x [1024,1024]^T + x
  gemm_bt<2><<<32 * 8, 256, 0, stream>>>(attn, woT, 8, out, x);
}

// Round 5
// 149.118 us; speedup vs baseline: 1.7997x; 1.7997x over previous
//
#include <hip/hip_runtime.h>
#include <stdint.h>

typedef __bf16 bf16;
typedef __bf16 bf16x2 __attribute__((ext_vector_type(2)));
typedef __bf16 bf16x4 __attribute__((ext_vector_type(4)));
typedef __bf16 bf16x8 __attribute__((ext_vector_type(8)));
typedef float f32x4 __attribute__((ext_vector_type(4)));

#define D_MODEL 1024
#define NHEADS 16
#define HEADDIM 64
#define SEQ 2048
#define NBATCH 2

__device__ __forceinline__ void async_load16(const void* g, void* l) {
  __builtin_amdgcn_global_load_lds(
      (__attribute__((address_space(1))) void*)g,
      (__attribute__((address_space(3))) void*)l, 16, 0, 0);
}

__device__ __forceinline__ float fexp2(float x) {
#if __has_builtin(__builtin_amdgcn_exp2f)
  return __builtin_amdgcn_exp2f(x);
#else
  return exp2f(x);
#endif
}

// ---------------- LayerNorm: fp32 x -> bf16 y ----------------
__global__ __launch_bounds__(256)
void ln_kernel(const float* __restrict__ x, const float* __restrict__ w,
               const float* __restrict__ b, bf16* __restrict__ y) {
  int row = blockIdx.x;
  int t = threadIdx.x;
  const float4 v = ((const float4*)(x + (size_t)row * D_MODEL))[t];
  float s = v.x + v.y + v.z + v.w;
  float sq = v.x * v.x + v.y * v.y + v.z * v.z + v.w * v.w;
#pragma unroll
  for (int d = 1; d < 64; d <<= 1) {
    s += __shfl_xor(s, d);
    sq += __shfl_xor(sq, d);
  }
  __shared__ float ps[4], pq[4];
  if ((t & 63) == 0) { ps[t >> 6] = s; pq[t >> 6] = sq; }
  __syncthreads();
  s = ps[0] + ps[1] + ps[2] + ps[3];
  sq = pq[0] + pq[1] + pq[2] + pq[3];
  float mean = s * (1.0f / D_MODEL);
  float var = sq * (1.0f / D_MODEL) - mean * mean;
  float rstd = rsqrtf(var + 1e-5f);
  float4 wv = ((const float4*)w)[t];
  float4 bv = ((const float4*)b)[t];
  bf16x4 o;
  o[0] = (bf16)((v.x - mean) * rstd * wv.x + bv.x);
  o[1] = (bf16)((v.y - mean) * rstd * wv.y + bv.y);
  o[2] = (bf16)((v.z - mean) * rstd * wv.z + bv.z);
  o[3] = (bf16)((v.w - mean) * rstd * wv.w + bv.w);
  ((bf16x4*)(y + (size_t)row * D_MODEL))[t] = o;
}

// ------------- transpose + cast: src fp32 [R][C] -> dst bf16 [C][R] -------------
__global__ __launch_bounds__(256)
void transpose_cast(const float* __restrict__ src, bf16* __restrict__ dst,
                    int src_ld, int dst_ld, int tiles_c,
                    long src_bstride, long dst_bstride) {
  __shared__ float tile[64][65];
  int tr = blockIdx.x / tiles_c, tc = blockIdx.x % tiles_c;
  const float* s = src + (long)blockIdx.y * src_bstride + (size_t)(tr * 64) * src_ld + (size_t)tc * 64;
  bf16* d = dst + (long)blockIdx.y * dst_bstride + (size_t)(tc * 64) * dst_ld + (size_t)tr * 64;
  int t = threadIdx.x;
  int rr = t >> 4;
  int cc = (t & 15) << 2;
#pragma unroll
  for (int i = 0; i < 4; ++i) {
    float4 v = *(const float4*)&s[(size_t)(rr + i * 16) * src_ld + cc];
    tile[rr + i * 16][cc + 0] = v.x;
    tile[rr + i * 16][cc + 1] = v.y;
    tile[rr + i * 16][cc + 2] = v.z;
    tile[rr + i * 16][cc + 3] = v.w;
  }
  __syncthreads();
#pragma unroll
  for (int i = 0; i < 4; ++i) {
    int drow = rr + i * 16;
    bf16x4 o;
    o[0] = (bf16)tile[cc + 0][drow];
    o[1] = (bf16)tile[cc + 1][drow];
    o[2] = (bf16)tile[cc + 2][drow];
    o[3] = (bf16)tile[cc + 3][drow];
    *(bf16x4*)&d[(size_t)drow * dst_ld + cc] = o;
  }
}

// ------------- GEMM: C[M][N] = A[M][K=1024] * Bt[N][K=1024]^T -------------
// v2: double-buffered LDS (prefetch next K-tile before computing current,
// one barrier per iter), XOR-swizzled staging (source chunk ^= row&7 on 16B
// granularity; fragment reads apply the same XOR) -> conflict-free ds_read,
// XCD-bijective block swizzle (grid % 8 == 0 for all call sites).
template <int MODE>
__global__ __launch_bounds__(256)
void gemm_bt(const bf16* __restrict__ A, const bf16* __restrict__ Bt,
             int ntn, void* __restrict__ p0, const void* __restrict__ p1) {
  __shared__ __align__(16) bf16 As[2][128 * 64];
  __shared__ __align__(16) bf16 Bs[2][128 * 64];
  int cpx = gridDim.x >> 3;
  int wg = (blockIdx.x & 7) * cpx + (blockIdx.x >> 3);
  int bm = wg / ntn;
  int bn = wg % ntn;
  int t = threadIdx.x;
  int w = t >> 6, l = t & 63;
  int lg = l >> 4, lo = l & 15;
  int wr = w >> 1, wc = w & 1;
  const bf16* Ab = A + (size_t)bm * 128 * 1024;
  const bf16* Bb = Bt + (size_t)bn * 128 * 1024;
  f32x4 acc[4][4];
#pragma unroll
  for (int i = 0; i < 4; ++i)
#pragma unroll
    for (int j = 0; j < 4; ++j) acc[i][j] = (f32x4){0.f, 0.f, 0.f, 0.f};

  auto stage = [&](int buf, int k0) {
#pragma unroll
    for (int i = 0; i < 4; ++i) {
      int flat = i * 2048 + t * 8;
      int row = flat >> 6, c16 = (flat & 63) >> 3;
      int sc = c16 ^ (row & 7);  // pre-swizzled source -> linear LDS dest
      async_load16(Ab + (size_t)row * 1024 + k0 + sc * 8, &As[buf][i * 2048 + w * 512]);
      async_load16(Bb + (size_t)row * 1024 + k0 + sc * 8, &Bs[buf][i * 2048 + w * 512]);
    }
  };

  stage(0, 0);
  __syncthreads();
  int buf = 0;
  for (int k0 = 0; k0 < 1024; k0 += 64) {
    if (k0 + 64 < 1024) stage(buf ^ 1, k0 + 64);  // async prefetch, flies across compute
#pragma unroll
    for (int kk = 0; kk < 2; ++kk) {
      bf16x8 af[4], bfr[4];
#pragma unroll
      for (int i = 0; i < 4; ++i) {
        int row = wr * 64 + i * 16 + lo;
        af[i] = *(const bf16x8*)&As[buf][row * 64 + (((4 * kk + lg) ^ (lo & 7)) * 8)];
      }
#pragma unroll
      for (int j = 0; j < 4; ++j) {
        int row = wc * 64 + j * 16 + lo;
        bfr[j] = *(const bf16x8*)&Bs[buf][row * 64 + (((4 * kk + lg) ^ (lo & 7)) * 8)];
      }
#pragma unroll
      for (int i = 0; i < 4; ++i)
#pragma unroll
        for (int j = 0; j < 4; ++j)
          acc[i][j] = __builtin_amdgcn_mfma_f32_16x16x32_bf16(af[i], bfr[j], acc[i][j], 0, 0, 0);
    }
    __syncthreads();  // waves done reading buf; prefetch into buf^1 drained
    buf ^= 1;
  }

  int mbase = bm * 128 + wr * 64;
  int nbase = bn * 128 + wc * 64;
#pragma unroll
  for (int i = 0; i < 4; ++i) {
#pragma unroll
    for (int j = 0; j < 4; ++j) {
#pragma unroll
      for (int r = 0; r < 4; ++r) {
        int row = mbase + i * 16 + lg * 4 + r;
        int col = nbase + j * 16 + lo;
        float v = acc[i][j][r];
        if (MODE == 0) {
          bf16* dst = (bf16*)p0;
          int c = col;
          if (c >= 1024) { dst = (bf16*)((void*)p1); c -= 1024; }
          int h = c >> 6, e = c & 63;
          dst[((((size_t)(row >> 11) * NHEADS + h) * SEQ) + (row & 2047)) * HEADDIM + e] = (bf16)v;
        } else if (MODE == 1) {
          int h = row >> 6, e = row & 63;
          int b_ = col >> 11, s_ = col & 2047;
          ((bf16*)p0)[(((size_t)b_ * NHEADS + h) * HEADDIM + e) * SEQ + s_] = (bf16)v;
        } else {
          float xr = ((const float*)p1)[(size_t)row * 1024 + col];
          ((float*)p0)[(size_t)row * 1024 + col] = v + xr;
        }
      }
    }
  }
}

// ------------- causal flash attention v5 -------------
// = v3 (LDS-staged K/V, double-buffered, swapped QK^T, in-lane softmax,
// defer-max, per-wave P round-trip — proven 71.9us) + v4's XCD-grouped block
// decode (proven FETCH 62.5 -> 12.3 MB): all 32 q-tiles of a bh pinned to one
// XCD, per-XCD K/V+Q working set ~3 MB < 4 MB L2.
__global__ __launch_bounds__(256)
void attn_kernel(const bf16* __restrict__ q, const bf16* __restrict__ k,
                 const bf16* __restrict__ vt, bf16* __restrict__ attn) {
  __shared__ __align__(16) bf16 Ks[2][64 * 64];
  __shared__ __align__(16) bf16 Vs[2][64 * 64];
  __shared__ __align__(16) bf16 P[4][16 * 64];
  const float C2 = 0.125f * 1.44269504f;  // fold 1/sqrt(64) into exp2 arg
  int i = blockIdx.x;
  int slot = i >> 3;
  int bh = (i & 7) + 8 * (slot >> 5);  // assumes round-robin dispatch i -> XCD i%8
  int tile = 31 - (slot & 31);         // heavy causal tiles first within group
  int b = bh >> 4, h = bh & 15;
  int t = threadIdx.x, w = t >> 6, l = t & 63;
  int lg = l >> 4, lo = l & 15;
  const bf16* qp = q + (size_t)bh * SEQ * HEADDIM;
  const bf16* kp = k + (size_t)bh * SEQ * HEADDIM;
  const bf16* vp = vt + (size_t)bh * HEADDIM * SEQ;
  int q0 = tile * 64 + w * 16;

  bf16x8 qf0 = *(const bf16x8*)&qp[(size_t)(q0 + lo) * HEADDIM + 8 * lg];
  bf16x8 qf1 = *(const bf16x8*)&qp[(size_t)(q0 + lo) * HEADDIM + 32 + 8 * lg];

  auto stage = [&](int buf, int kv0) {
#pragma unroll
    for (int it = 0; it < 2; ++it) {
      int slot2 = it * 256 + w * 64 + l;
      int row = slot2 >> 3, c16 = slot2 & 7;
      int sc = c16 ^ (row & 7);
      async_load16(kp + (size_t)(kv0 + row) * HEADDIM + sc * 8,
                   &Ks[buf][(it * 256 + w * 64) * 8]);
      async_load16(vp + (size_t)row * SEQ + kv0 + sc * 8,
                   &Vs[buf][(it * 256 + w * 64) * 8]);
    }
  };

  f32x4 o[4];
#pragma unroll
  for (int nt = 0; nt < 4; ++nt) o[nt] = (f32x4){0.f, 0.f, 0.f, 0.f};
  float m = -1e30f, lsum = 0.f;  // per-lane, q-row = q0 + lo (raw-score units)
  int diag_rhs = w * 16 + lo;    // kv-local visibility bound on diagonal chunk

  int buf = 0;
  stage(0, 0);
  __syncthreads();

  for (int c = 0; c <= tile; ++c) {
    if (c < tile) stage(buf ^ 1, (c + 1) * 64);  // async prefetch

    // S^T = K * Q^T : C[kv][q], lane owns q = lo, kv = 16*nt + 4*lg + r
    f32x4 s[4];
    __builtin_amdgcn_s_setprio(1);
#pragma unroll
    for (int nt = 0; nt < 4; ++nt) {
      s[nt] = (f32x4){0.f, 0.f, 0.f, 0.f};
      int krow = nt * 16 + lo;
      bf16x8 kf0 = *(const bf16x8*)&Ks[buf][krow * 64 + ((lg ^ (lo & 7)) * 8)];
      bf16x8 kf1 = *(const bf16x8*)&Ks[buf][krow * 64 + (((4 + lg) ^ (lo & 7)) * 8)];
      s[nt] = __builtin_amdgcn_mfma_f32_16x16x32_bf16(kf0, qf0, s[nt], 0, 0, 0);
      s[nt] = __builtin_amdgcn_mfma_f32_16x16x32_bf16(kf1, qf1, s[nt], 0, 0, 0);
    }
    __builtin_amdgcn_s_setprio(0);

    if (c == tile) {  // causal mask, diagonal chunk only (uniform branch)
#pragma unroll
      for (int nt = 0; nt < 4; ++nt)
#pragma unroll
        for (int r = 0; r < 4; ++r)
          s[nt][r] = (16 * nt + 4 * lg + r <= diag_rhs) ? s[nt][r] : -1e30f;
    }

    // in-lane max tree (16 values) + 2 cross-group shuffles
    float mx0 = fmaxf(fmaxf(s[0][0], s[0][1]), fmaxf(s[0][2], s[0][3]));
    float mx1 = fmaxf(fmaxf(s[1][0], s[1][1]), fmaxf(s[1][2], s[1][3]));
    float mx2 = fmaxf(fmaxf(s[2][0], s[2][1]), fmaxf(s[2][2], s[2][3]));
    float mx3 = fmaxf(fmaxf(s[3][0], s[3][1]), fmaxf(s[3][2], s[3][3]));
    float pmax = fmaxf(fmaxf(mx0, mx1), fmaxf(mx2, mx3));
    pmax = fmaxf(pmax, __shfl_xor(pmax, 16));
    pmax = fmaxf(pmax, __shfl_xor(pmax, 32));

    // defer-max: rescale only if some row's max grew past threshold (40 raw = 5 nats)
    if (__any(pmax > m + 40.0f)) {
      float mn = fmaxf(m, pmax);
      float alpha = fexp2((m - mn) * C2);
      m = mn;
      lsum *= alpha;
#pragma unroll
      for (int r = 0; r < 4; ++r) {
        float ar = __shfl(alpha, (l & 48) | (4 * lg + r));
        o[0][r] *= ar; o[1][r] *= ar; o[2][r] *= ar; o[3][r] *= ar;
      }
    }

    float mC = m * C2;
    float p[4][4];
    float psum[4];
#pragma unroll
    for (int nt = 0; nt < 4; ++nt) {
      psum[nt] = 0.f;
#pragma unroll
      for (int r = 0; r < 4; ++r) {
        float e = fexp2(fmaf(s[nt][r], C2, -mC));
        p[nt][r] = e;
        psum[nt] += e;
      }
    }
    float pst = (psum[0] + psum[1]) + (psum[2] + psum[3]);
    pst += __shfl_xor(pst, 16);
    pst += __shfl_xor(pst, 32);
    lsum += pst;

    // P[q=lo][kv] -> per-wave LDS (swizzled), packed b32 writes
#pragma unroll
    for (int nt = 0; nt < 4; ++nt) {
      int chunk = (2 * nt + (lg >> 1)) ^ (lo & 7);
      int base = lo * 64 + chunk * 8 + 4 * (lg & 1);
      bf16x2 w0, w1;
      w0[0] = (bf16)p[nt][0]; w0[1] = (bf16)p[nt][1];
      w1[0] = (bf16)p[nt][2]; w1[1] = (bf16)p[nt][3];
      *(bf16x2*)&P[w][base] = w0;
      *(bf16x2*)&P[w][base + 2] = w1;
    }
    bf16x8 pf0 = *(const bf16x8*)&P[w][lo * 64 + ((lg ^ (lo & 7)) * 8)];
    bf16x8 pf1 = *(const bf16x8*)&P[w][lo * 64 + (((4 + lg) ^ (lo & 7)) * 8)];

    __builtin_amdgcn_s_setprio(1);
#pragma unroll
    for (int nt = 0; nt < 4; ++nt) {
      int vrow = nt * 16 + lo;
      bf16x8 vf0 = *(const bf16x8*)&Vs[buf][vrow * 64 + ((lg ^ (lo & 7)) * 8)];
      bf16x8 vf1 = *(const bf16x8*)&Vs[buf][vrow * 64 + (((4 + lg) ^ (lo & 7)) * 8)];
      o[nt] = __builtin_amdgcn_mfma_f32_16x16x32_bf16(pf0, vf0, o[nt], 0, 0, 0);
      o[nt] = __builtin_amdgcn_mfma_f32_16x16x32_bf16(pf1, vf1, o[nt], 0, 0, 0);
    }
    __builtin_amdgcn_s_setprio(0);

    __syncthreads();  // drains prefetch + all waves done reading buf
    buf ^= 1;
  }

#pragma unroll
  for (int r = 0; r < 4; ++r) {
    float ls = __shfl(lsum, (l & 48) | (4 * lg + r));
    float inv = 1.0f / ls;
    int qrow = q0 + 4 * lg + r;
#pragma unroll
    for (int nt = 0; nt < 4; ++nt)
      attn[((size_t)b * SEQ + qrow) * D_MODEL + h * HEADDIM + nt * 16 + lo] =
          (bf16)(o[nt][r] * inv);
  }
}

extern "C" void kernel_launch(void* const* d_in, const int* in_sizes, int n_in,
                              void* d_out, int out_size, void* d_ws, size_t ws_size,
                              hipStream_t stream) {
  const float* x = (const float*)d_in[0];
  const float* ln_w = (const float*)d_in[1];
  const float* ln_b = (const float*)d_in[2];
  const float* wq = (const float*)d_in[3];
  const float* wk = (const float*)d_in[4];
  const float* wv = (const float*)d_in[5];
  const float* wo = (const float*)d_in[6];
  float* out = (float*)d_out;
  char* ws = (char*)d_ws;

  bf16* y     = (bf16*)(ws);                     // 8 MB
  bf16* WqkvT = (bf16*)(ws + (8u << 20));        // 6 MB  [3072][1024]
  bf16* woT   = (bf16*)(ws + (14u << 20));       // 2 MB  [1024][1024]
  bf16* qb    = (bf16*)(ws + (16u << 20));       // 8 MB  [b][h][s][e]
  bf16* kb    = (bf16*)(ws + (24u << 20));       // 8 MB  [b][h][s][e]
  bf16* vtb   = (bf16*)(ws + (32u << 20));       // 8 MB  [b][h][e][s]
  bf16* attn  = (bf16*)(ws + (40u << 20));       // 8 MB  [b*s][h*e]

  // LayerNorm
  ln_kernel<<<NBATCH * SEQ, 256, 0, stream>>>(x, ln_w, ln_b, y);

  // weights -> k-contiguous bf16 transposes
  transpose_cast<<<dim3(16, 16), 256, 0, stream>>>(wq, WqkvT,                64, 1024, 1, 65536, 65536);
  transpose_cast<<<dim3(16, 16), 256, 0, stream>>>(wk, WqkvT + (1u << 20),   64, 1024, 1, 65536, 65536);
  transpose_cast<<<dim3(16, 16), 256, 0, stream>>>(wv, WqkvT + (2u << 20),   64, 1024, 1, 65536, 65536);
  transpose_cast<<<dim3(256, 1), 256, 0, stream>>>(wo, woT,                1024, 1024, 16, 0, 0);

  // q,k projections: [4096,1024] x [2048,1024]^T
  gemm_bt<0><<<32 * 16, 256, 0, stream>>>(y, WqkvT, 16, qb, kb);
  // v^T projection: [1024,1024] x [4096,1024]^T -> vt[b][h][e][s]
  gemm_bt<1><<<8 * 32, 256, 0, stream>>>(WqkvT + (2u << 20), y, 32, vtb, nullptr);

  // causal flash attention (1024 blocks, XCD-grouped decode in-kernel)
  attn_kernel<<<dim3(1024), 256, 0, stream>>>(qb, kb, vtb, attn);

  // output projection + residual: [4096,1024] x [1024,1024]^T + x
  gemm_bt<2><<<32 * 8, 256, 0, stream>>>(attn, woT, 8, out, x);
}